// Round 10
// baseline (11.447 us; speedup 1.0000x reference)
//
#include <hip/hip_runtime.h>
#include <math.h>

#define B_ROWS 8192
#define D_DIM 512
#define N_LABELS 256
#define GMAX 64              // max group size on MFMA path (P[exceed] ~ 1e-8; exact fallback below)
#define THREADS 1024
#define WAVES 16
#define SEG (B_ROWS / WAVES) // 512 rows scanned per wave
#define SITER (SEG / 64)     // 8 ballot iterations per wave
#define LSTRIDE (D_DIM + 8)  // 520 fp16 per row -> 1040 B stride (16B-aligned, 2-way bank alias only)
#define SMAX (GMAX * (D_DIM / 4) / THREADS)  // 8 static staging iterations

typedef __attribute__((ext_vector_type(8))) _Float16 f16x8;
typedef __attribute__((ext_vector_type(4))) float f32x4;

static __device__ __forceinline__ unsigned short f2h(float f) {
    const _Float16 h = (_Float16)f;       // v_cvt_f16_f32 (RNE)
    return __builtin_bit_cast(unsigned short, h);
}

// One block per label; 16 waves; single fused kernel (round-9 structure, best
// measured at 11.08 us). Round-10 change: staging loop statically unrolled to
// SMAX=8 iterations with clamped-address unconditional loads + conditional
// stores, so all gather loads issue into ONE latency window instead of a
// serial load->wait->write chain per iteration.
__global__ __launch_bounds__(THREADS) void loss_kernel(const float* __restrict__ z,
                                                       const int* __restrict__ Mx,
                                                       float* __restrict__ out) {
    __shared__ __align__(16) unsigned short h_sh[GMAX][LSTRIDE];  // 66,560 B
    __shared__ int   ids_sh[GMAX];
    __shared__ float sq_sh[GMAX];
    __shared__ float rowpart[WAVES][GMAX];                        // 4 KB
    __shared__ int   wcnt[WAVES], wbase[WAVES];
    __shared__ int   cnt_sh;

    const int lbl  = blockIdx.x;
    const int tid  = threadIdx.x;
    const int wv   = tid >> 6;
    const int lane = tid & 63;
    const int sb   = wv * SEG;

    // ---- P1: ballot scan; masks stay in registers (wave-uniform) ----
    unsigned long long bal[SITER];
    int c = 0;
    #pragma unroll
    for (int t = 0; t < SITER; ++t) {
        bal[t] = __ballot(Mx[sb + t * 64 + lane] == lbl);
        c += __popcll(bal[t]);
    }
    if (lane == 0) wcnt[wv] = c;
    for (int i = tid; i < WAVES * GMAX; i += THREADS) ((float*)rowpart)[i] = 0.f;
    __syncthreads();                                   // B1

    // ---- P2: parallel 16-lane inclusive scan in wave 0 ----
    if (wv == 0) {
        int v = (lane < WAVES) ? wcnt[lane] : 0;
        #pragma unroll
        for (int d = 1; d < WAVES; d <<= 1) {
            const int o = __shfl_up(v, d, 64);
            if (lane >= d) v += o;
        }
        if (lane < WAVES) wbase[lane] = v - wcnt[lane];
        if (lane == WAVES - 1) cnt_sh = v;
    }
    __syncthreads();                                   // B2
    const int cnt = cnt_sh;
    if (cnt <= 0) return;

    if (cnt > GMAX) {
        // exact fp32 fallback (statistically never runs; correctness guard)
        int k = 0;
        for (int i = 0; i < B_ROWS; ++i) {
            if (Mx[i] != lbl) continue;
            if ((k++ % WAVES) != wv) continue;
            float acc2 = 0.f;
            for (int j = 0; j < B_ROWS; ++j) {
                if (Mx[j] != lbl || j == i) continue;
                float s = 0.f;
                for (int d = lane; d < D_DIM; d += 64) {
                    const float t = z[(size_t)i * D_DIM + d] - z[(size_t)j * D_DIM + d];
                    s = fmaf(t, t, s);
                }
                s += __shfl_xor(s, 1, 64);
                s += __shfl_xor(s, 2, 64);
                s += __shfl_xor(s, 4, 64);
                s += __shfl_xor(s, 8, 64);
                s += __shfl_xor(s, 16, 64);
                s += __shfl_xor(s, 32, 64);
                acc2 += (s > 0.f) ? sqrtf(s) : 0.f;
            }
            if (lane == 0) out[i] = acc2 / (float)(cnt - 1);
        }
        return;
    }

    // ---- P1b: stable rank scatter of ids from register masks ----
    {
        int pos = wbase[wv];
        const unsigned long long lower = (lane == 0) ? 0ull : ((1ull << lane) - 1ull);
        #pragma unroll
        for (int t = 0; t < SITER; ++t) {
            const unsigned long long b = bal[t];
            if ((b >> lane) & 1ull)
                ids_sh[pos + __popcll(b & lower)] = sb + t * 64 + lane;
            pos += __popcll(b);
        }
    }
    __syncthreads();                                   // B3

    // ---- P3: staging, statically unrolled; clamped loads, conditional stores ----
    {
        const int limit = cnt * (D_DIM / 4);           // active c2 range
        float4 vv[SMAX];
        int    rowv[SMAX], colv[SMAX];
        #pragma unroll
        for (int k = 0; k < SMAX; ++k) {
            const int c2  = tid + k * THREADS;
            const int c2c = (c2 < limit) ? c2 : (limit - 1);   // clamp -> always-valid addr
            rowv[k] = c2c >> 7;                         // D_DIM/4 == 128
            colv[k] = c2c & 127;
            vv[k] = *(const float4*)(z + (size_t)ids_sh[rowv[k]] * D_DIM + colv[k] * 4);
        }
        #pragma unroll
        for (int k = 0; k < SMAX; ++k) {
            const int c2 = tid + k * THREADS;
            if (c2 < limit) {
                const float4 v = vv[k];
                const unsigned int p0 = (unsigned int)f2h(v.x) | ((unsigned int)f2h(v.y) << 16);
                const unsigned int p1 = (unsigned int)f2h(v.z) | ((unsigned int)f2h(v.w) << 16);
                *(uint2*)&h_sh[rowv[k]][colv[k] * 4] = make_uint2(p0, p1);
            }
        }
    }
    __syncthreads();                                   // B4

    // ---- P4: MFMA fp16 gram, upper-triangle tiles, one tile per wave ----
    const int NT = (cnt + 15) >> 4;           // 1..4
    const int TS = NT * (NT + 1) / 2;         // 1,3,6,10

    int jt = 0;
    #pragma unroll
    for (int q = 1; q < 4; ++q) jt += (wv >= q * (q + 1) / 2);  // wv -> (it,jt) col-major tri
    const int it = wv - jt * (jt + 1) / 2;
    const bool own = (wv < TS);

    const int l15 = lane & 15;
    const int lh  = lane >> 4;                // 0..3

    f32x4 acc = {0.f, 0.f, 0.f, 0.f};
    if (own) {
        #pragma unroll
        for (int k4 = 0; k4 < D_DIM / 32; ++k4) {
            const int kb = k4 * 32 + lh * 8;
            const f16x8 a = *(const f16x8*)&h_sh[it * 16 + l15][kb];
            const f16x8 b = *(const f16x8*)&h_sh[jt * 16 + l15][kb];
            acc = __builtin_amdgcn_mfma_f32_16x16x32_f16(a, b, acc, 0, 0, 0);
        }
    }

    // ---- P4a: gram diagonal = |z_h|^2 (diagonal tiles only) ----
    // C/D layout (m89-verified): col = lane&15, row = (lane>>4)*4 + reg
    if (own && it == jt) {
        #pragma unroll
        for (int r = 0; r < 4; ++r) {
            const int drow = lh * 4 + r;
            if (l15 == drow) sq_sh[it * 16 + drow] = acc[r];
        }
    }
    __syncthreads();                                   // B5

    // ---- P4b: distances; row sums + (off-diag) column sums ----
    if (own) {
        float d0 = 0.f, d1 = 0.f, d2v = 0.f, d3 = 0.f;
        #pragma unroll
        for (int r = 0; r < 4; ++r) {
            const int gi = it * 16 + lh * 4 + r;
            const int gj = jt * 16 + l15;
            const float d2 = sq_sh[gi] + sq_sh[gj] - 2.f * acc[r];
            const bool valid = (gi < cnt) && (gj < cnt) && (gi != gj) && (d2 > 0.f);
            const float dist = valid ? sqrtf(d2) : 0.f;
            if (r == 0) d0 = dist; else if (r == 1) d1 = dist; else if (r == 2) d2v = dist; else d3 = dist;

            float rs = dist;
            rs += __shfl_xor(rs, 1, 64);
            rs += __shfl_xor(rs, 2, 64);
            rs += __shfl_xor(rs, 4, 64);
            rs += __shfl_xor(rs, 8, 64);
            if (l15 == 0) rowpart[wv][gi] += rs;
        }
        if (it != jt) {
            float cs = (d0 + d1) + (d2v + d3);  // sum over this lane's 4 rows
            cs += __shfl_xor(cs, 16, 64);
            cs += __shfl_xor(cs, 32, 64);       // sum over all 16 rows of the tile
            if (lane < 16) rowpart[wv][jt * 16 + l15] += cs;
        }
    }
    __syncthreads();                                   // B6

    // ---- final reduce over waves + write ----
    if (tid < cnt) {
        float s = 0.f;
        #pragma unroll
        for (int w = 0; w < WAVES; ++w) s += rowpart[w][tid];
        out[ids_sh[tid]] = (cnt > 1) ? s / (float)(cnt - 1) : 0.f;
    }
}

// ---------------- launch ----------------
extern "C" void kernel_launch(void* const* d_in, const int* in_sizes, int n_in,
                              void* d_out, int out_size, void* d_ws, size_t ws_size,
                              hipStream_t stream) {
    const float* z  = (const float*)d_in[0];
    const int*   Mx = (const int*)d_in[1];
    float*       out = (float*)d_out;

    loss_kernel<<<N_LABELS, THREADS, 0, stream>>>(z, Mx, out);
}

// Round 11
// 11.076 us; speedup vs baseline: 1.0335x; 1.0335x over previous
//
#include <hip/hip_runtime.h>
#include <math.h>

#define B_ROWS 8192
#define D_DIM 512
#define N_LABELS 256
#define GMAX 64              // max group size on MFMA path (P[exceed] ~ 1e-8; exact fallback below)
#define THREADS 1024
#define WAVES 16
#define SEG (B_ROWS / WAVES) // 512 rows scanned per wave
#define SITER (SEG / 64)     // 8 ballot iterations per wave
#define LSTRIDE (D_DIM + 8)  // 520 fp16 per row -> 1040 B stride (16B-aligned, 2-way bank alias only)

typedef __attribute__((ext_vector_type(8))) _Float16 f16x8;
typedef __attribute__((ext_vector_type(4))) float f32x4;

static __device__ __forceinline__ unsigned short f2h(float f) {
    const _Float16 h = (_Float16)f;       // v_cvt_f16_f32 (RNE)
    return __builtin_bit_cast(unsigned short, h);
}

// EXACT round-9 kernel (best measured: 11.08 us). Round-10's static-unroll
// staging regressed (11.45 us + replay pathology) and is reverted.
// One block per label; 16 waves; single fused kernel.
// P1 : ballot-scan Mx once, masks kept in REGISTERS; rowpart zeroed here.
// P2 : 16-lane shfl prefix -> wbase/cnt.
// P1b: per-wave stable rank scatter of ids from register masks.
// P3 : fully-distributed staging pass, fp32 -> fp16 LDS (all 1024 threads).
// P4 : MFMA fp16 gram, upper-triangle tiles, one 16x16 tile per wave.
// P4a: gram diagonal -> |z_h|^2 (consistent quantization).
// P4b: distances; row sums + off-diag column sums; final reduce.
__global__ __launch_bounds__(THREADS) void loss_kernel(const float* __restrict__ z,
                                                       const int* __restrict__ Mx,
                                                       float* __restrict__ out) {
    __shared__ __align__(16) unsigned short h_sh[GMAX][LSTRIDE];  // 66,560 B
    __shared__ int   ids_sh[GMAX];
    __shared__ float sq_sh[GMAX];
    __shared__ float rowpart[WAVES][GMAX];                        // 4 KB
    __shared__ int   wcnt[WAVES], wbase[WAVES];
    __shared__ int   cnt_sh;

    const int lbl  = blockIdx.x;
    const int tid  = threadIdx.x;
    const int wv   = tid >> 6;
    const int lane = tid & 63;
    const int sb   = wv * SEG;

    // ---- P1: ballot scan; masks stay in registers (wave-uniform) ----
    unsigned long long bal[SITER];
    int c = 0;
    #pragma unroll
    for (int t = 0; t < SITER; ++t) {
        bal[t] = __ballot(Mx[sb + t * 64 + lane] == lbl);
        c += __popcll(bal[t]);
    }
    if (lane == 0) wcnt[wv] = c;
    for (int i = tid; i < WAVES * GMAX; i += THREADS) ((float*)rowpart)[i] = 0.f;
    __syncthreads();                                   // B1

    // ---- P2: parallel 16-lane inclusive scan in wave 0 ----
    if (wv == 0) {
        int v = (lane < WAVES) ? wcnt[lane] : 0;
        #pragma unroll
        for (int d = 1; d < WAVES; d <<= 1) {
            const int o = __shfl_up(v, d, 64);
            if (lane >= d) v += o;
        }
        if (lane < WAVES) wbase[lane] = v - wcnt[lane];
        if (lane == WAVES - 1) cnt_sh = v;
    }
    __syncthreads();                                   // B2
    const int cnt = cnt_sh;
    if (cnt <= 0) return;

    if (cnt > GMAX) {
        // exact fp32 fallback (statistically never runs; correctness guard)
        int k = 0;
        for (int i = 0; i < B_ROWS; ++i) {
            if (Mx[i] != lbl) continue;
            if ((k++ % WAVES) != wv) continue;
            float acc2 = 0.f;
            for (int j = 0; j < B_ROWS; ++j) {
                if (Mx[j] != lbl || j == i) continue;
                float s = 0.f;
                for (int d = lane; d < D_DIM; d += 64) {
                    const float t = z[(size_t)i * D_DIM + d] - z[(size_t)j * D_DIM + d];
                    s = fmaf(t, t, s);
                }
                s += __shfl_xor(s, 1, 64);
                s += __shfl_xor(s, 2, 64);
                s += __shfl_xor(s, 4, 64);
                s += __shfl_xor(s, 8, 64);
                s += __shfl_xor(s, 16, 64);
                s += __shfl_xor(s, 32, 64);
                acc2 += (s > 0.f) ? sqrtf(s) : 0.f;
            }
            if (lane == 0) out[i] = acc2 / (float)(cnt - 1);
        }
        return;
    }

    // ---- P1b: stable rank scatter of ids from register masks ----
    {
        int pos = wbase[wv];
        const unsigned long long lower = (lane == 0) ? 0ull : ((1ull << lane) - 1ull);
        #pragma unroll
        for (int t = 0; t < SITER; ++t) {
            const unsigned long long b = bal[t];
            if ((b >> lane) & 1ull)
                ids_sh[pos + __popcll(b & lower)] = sb + t * 64 + lane;
            pos += __popcll(b);
        }
    }
    __syncthreads();                                   // B3

    // ---- P3: fully-distributed staging pass, fp32 -> fp16 ----
    for (int c2 = tid; c2 < cnt * (D_DIM / 4); c2 += THREADS) {
        const int row = c2 >> 7;              // D_DIM/4 == 128
        const int c4  = c2 & 127;
        const float4 v = *(const float4*)(z + (size_t)ids_sh[row] * D_DIM + c4 * 4);
        const unsigned int p0 = (unsigned int)f2h(v.x) | ((unsigned int)f2h(v.y) << 16);
        const unsigned int p1 = (unsigned int)f2h(v.z) | ((unsigned int)f2h(v.w) << 16);
        *(uint2*)&h_sh[row][c4 * 4] = make_uint2(p0, p1);
    }
    __syncthreads();                                   // B4

    // ---- P4: MFMA fp16 gram, upper-triangle tiles, one tile per wave ----
    const int NT = (cnt + 15) >> 4;           // 1..4
    const int TS = NT * (NT + 1) / 2;         // 1,3,6,10

    int jt = 0;
    #pragma unroll
    for (int q = 1; q < 4; ++q) jt += (wv >= q * (q + 1) / 2);  // wv -> (it,jt) col-major tri
    const int it = wv - jt * (jt + 1) / 2;
    const bool own = (wv < TS);

    const int l15 = lane & 15;
    const int lh  = lane >> 4;                // 0..3

    f32x4 acc = {0.f, 0.f, 0.f, 0.f};
    if (own) {
        #pragma unroll
        for (int k4 = 0; k4 < D_DIM / 32; ++k4) {
            const int kb = k4 * 32 + lh * 8;
            const f16x8 a = *(const f16x8*)&h_sh[it * 16 + l15][kb];
            const f16x8 b = *(const f16x8*)&h_sh[jt * 16 + l15][kb];
            acc = __builtin_amdgcn_mfma_f32_16x16x32_f16(a, b, acc, 0, 0, 0);
        }
    }

    // ---- P4a: gram diagonal = |z_h|^2 (diagonal tiles only) ----
    // C/D layout (m89-verified): col = lane&15, row = (lane>>4)*4 + reg
    if (own && it == jt) {
        #pragma unroll
        for (int r = 0; r < 4; ++r) {
            const int drow = lh * 4 + r;
            if (l15 == drow) sq_sh[it * 16 + drow] = acc[r];
        }
    }
    __syncthreads();                                   // B5

    // ---- P4b: distances; row sums + (off-diag) column sums ----
    if (own) {
        float d0 = 0.f, d1 = 0.f, d2v = 0.f, d3 = 0.f;
        #pragma unroll
        for (int r = 0; r < 4; ++r) {
            const int gi = it * 16 + lh * 4 + r;
            const int gj = jt * 16 + l15;
            const float d2 = sq_sh[gi] + sq_sh[gj] - 2.f * acc[r];
            const bool valid = (gi < cnt) && (gj < cnt) && (gi != gj) && (d2 > 0.f);
            const float dist = valid ? sqrtf(d2) : 0.f;
            if (r == 0) d0 = dist; else if (r == 1) d1 = dist; else if (r == 2) d2v = dist; else d3 = dist;

            float rs = dist;
            rs += __shfl_xor(rs, 1, 64);
            rs += __shfl_xor(rs, 2, 64);
            rs += __shfl_xor(rs, 4, 64);
            rs += __shfl_xor(rs, 8, 64);
            if (l15 == 0) rowpart[wv][gi] += rs;
        }
        if (it != jt) {
            float cs = (d0 + d1) + (d2v + d3);  // sum over this lane's 4 rows
            cs += __shfl_xor(cs, 16, 64);
            cs += __shfl_xor(cs, 32, 64);       // sum over all 16 rows of the tile
            if (lane < 16) rowpart[wv][jt * 16 + l15] += cs;
        }
    }
    __syncthreads();                                   // B6

    // ---- final reduce over waves + write ----
    if (tid < cnt) {
        float s = 0.f;
        #pragma unroll
        for (int w = 0; w < WAVES; ++w) s += rowpart[w][tid];
        out[ids_sh[tid]] = (cnt > 1) ? s / (float)(cnt - 1) : 0.f;
    }
}

// ---------------- launch ----------------
extern "C" void kernel_launch(void* const* d_in, const int* in_sizes, int n_in,
                              void* d_out, int out_size, void* d_ws, size_t ws_size,
                              hipStream_t stream) {
    const float* z  = (const float*)d_in[0];
    const int*   Mx = (const int*)d_in[1];
    float*       out = (float*)d_out;

    loss_kernel<<<N_LABELS, THREADS, 0, stream>>>(z, Mx, out);
}